// Round 16
// baseline (197.809 us; speedup 1.0000x reference)
//
#include <hip/hip_runtime.h>

// ---------------------------------------------------------------------------
// MHA forward. B=2 L=2048 D=1024 H=16 dk=dv=64.
// d_out = [out: 4194304 f32][attn: 134217728 f32]
// ws (40MB): wq|wk|wv|wo bf16 @0,2,4,6MB; q_b@8; k_b@16; vT@24; ctx@32
// Order: cvt_w -> fused QKV (Q prescaled by 0.125/ln2) -> attn (exp2) -> out
// attn: phase1 KVBLK=128, THREE buffers, 2-deep counted-vmcnt prefetch;
// phase2 single-barrier dbuf loop (R15), counted-vmcnt NT-store pipe.
// 48KB LDS union, 3 blocks/CU.
// ---------------------------------------------------------------------------

typedef unsigned short u16;
typedef unsigned int   u32;
typedef __attribute__((ext_vector_type(4))) float f32x4;
typedef __attribute__((ext_vector_type(8))) u16   u16x8;
typedef __attribute__((ext_vector_type(4))) u16   u16x4;
typedef __attribute__((ext_vector_type(8))) __bf16 bf16x8;

#define MFMA16(a, b, c) __builtin_amdgcn_mfma_f32_16x16x32_bf16((a), (b), (c), 0, 0, 0)
#define VMCNT0 asm volatile("s_waitcnt vmcnt(0)" ::: "memory")
#define VMCNT4 asm volatile("s_waitcnt vmcnt(4)" ::: "memory")
#define SCHED0 __builtin_amdgcn_sched_barrier(0)
#define RAWBAR __builtin_amdgcn_s_barrier()

#if defined(__has_builtin)
#if __has_builtin(__builtin_amdgcn_global_load_lds)
#define HAS_GLL 1
#endif
#if __has_builtin(__builtin_amdgcn_exp2f)
#define EXP2(x) __builtin_amdgcn_exp2f(x)
#endif
#endif
#ifndef HAS_GLL
#define HAS_GLL 0
#endif
#ifndef EXP2
#define EXP2(x) __expf((x) * 0.69314718056f)
#endif

#define QSCALE 0.18033688011116f   // 0.125 / ln(2)

__device__ __forceinline__ u16 f2bf(float x) {
    u32 u = __builtin_bit_cast(u32, x);
    u += 0x7fffu + ((u >> 16) & 1u);   // RNE
    return (u16)(u >> 16);
}
__device__ __forceinline__ float bf2f(u16 x) {
    u32 u = ((u32)x) << 16;
    return __builtin_bit_cast(float, u);
}
__device__ __forceinline__ bf16x8 ld8(const u16* p) {
    return __builtin_bit_cast(bf16x8, *(const u16x8*)p);
}

// async global->LDS, 16B per lane; lds_base wave-uniform, HW adds lane*16.
__device__ __forceinline__ void stage16(const u16* g, u16* lds_base, int lane) {
#if HAS_GLL
    (void)lane;
    __builtin_amdgcn_global_load_lds(
        (const __attribute__((address_space(1))) u32*)g,
        (__attribute__((address_space(3))) u32*)lds_base, 16, 0, 0);
#else
    *(u16x8*)((char*)lds_base + lane * 16) = *(const u16x8*)g;
#endif
}

// ---------------- fp32 -> bf16 conversion (weights only) -------------------
__global__ __launch_bounds__(256) void cvt_w(
    const float* __restrict__ wq, const float* __restrict__ wk,
    const float* __restrict__ wv, const float* __restrict__ wo,
    u16* __restrict__ wqb, u16* __restrict__ wkb,
    u16* __restrict__ wvb, u16* __restrict__ wob) {
    int bid = blockIdx.x;
    const float* src; u16* dst; int base;
    if      (bid < 1024) { src = wq; dst = wqb; base = bid; }
    else if (bid < 2048) { src = wk; dst = wkb; base = bid - 1024; }
    else if (bid < 3072) { src = wv; dst = wvb; base = bid - 2048; }
    else                 { src = wo; dst = wob; base = bid - 3072; }
    int i = (base * 256 + threadIdx.x) * 4;
    float4 v = *(const float4*)(src + i);
    u16x4 h = { f2bf(v.x), f2bf(v.y), f2bf(v.z), f2bf(v.w) };
    *(u16x4*)(dst + i) = h;
}

// ---------------- fused QKV projection (R12/R13 proven, XCD-pinned) --------
__global__ __launch_bounds__(256)
void k_qkv(const float* __restrict__ qa, const float* __restrict__ ka,
           const float* __restrict__ va,
           const u16* __restrict__ wqp, const u16* __restrict__ wkp,
           const u16* __restrict__ wvp,
           u16* __restrict__ qo, u16* __restrict__ ko, u16* __restrict__ vTo) {
    constexpr int K = 1024;
    __shared__ u16 act_lds[2][128][32];
    __shared__ u16 w_lds[2][128][32];

    const int tid = threadIdx.x, lane = tid & 63, w = tid >> 6;
    const int wr = w >> 1, wc = w & 1, lr = lane & 15, g0 = lane >> 4;
    const int bid0 = blockIdx.x;
    const int kk = bid0 / 96, gg = bid0 % 96;      // XCD-pinned remap
    const int wgid = gg * 8 + kk;
    const int region = wgid >> 8, r = wgid & 255;
    const int act_r0 = (r >> 3) * 128, w_r0 = (r & 7) * 128;

    const float* actp = region == 0 ? qa : region == 1 ? ka : va;
    const u16*   wp   = region == 0 ? wqp : region == 1 ? wkp : wvp;

    const int srow = lane >> 2;
    const int scol = ((lane & 3) ^ ((lane >> 3) & 3)) * 8;
    const int arow = tid >> 1, ac0 = (tid & 1) * 16, lg0 = (tid & 1) * 2;
    const int apg0 = ((lg0)     ^ ((arow >> 1) & 3)) * 8;
    const int apg1 = ((lg0 + 1) ^ ((arow >> 1) & 3)) * 8;
    const int aph = (g0 ^ ((lr >> 1) & 3)) * 8;

    auto stage = [&](int kt, int buf) {
        #pragma unroll
        for (int c = 0; c < 2; ++c) {
            int rb = w * 16 + c * 64;
            stage16(wp + (size_t)(w_r0 + rb + srow) * K + kt * 32 + scol,
                    &w_lds[buf][rb][0], lane);
        }
        const float* as = actp + (size_t)(act_r0 + arow) * K + kt * 32 + ac0;
        f32x4 v0 = *(const f32x4*)as;
        f32x4 v1 = *(const f32x4*)(as + 4);
        f32x4 v2 = *(const f32x4*)(as + 8);
        f32x4 v3 = *(const f32x4*)(as + 12);
        u16x8 h0 = { f2bf(v0[0]), f2bf(v0[1]), f2bf(v0[2]), f2bf(v0[3]),
                     f2bf(v1[0]), f2bf(v1[1]), f2bf(v1[2]), f2bf(v1[3]) };
        u16x8 h1 = { f2bf(v2[0]), f2bf(v2[1]), f2bf(v2[2]), f2bf(v2[3]),
                     f2bf(v3[0]), f2bf(v3[1]), f2bf(v3[2]), f2bf(v3[3]) };
        *(u16x8*)&act_lds[buf][arow][apg0] = h0;
        *(u16x8*)&act_lds[buf][arow][apg1] = h1;
    };

    f32x4 acc[4][4] = {};
    stage(0, 0);
    VMCNT0;
    __syncthreads();

    for (int kt = 0; kt < 32; ++kt) {
        if (kt + 1 < 32) stage(kt + 1, (kt + 1) & 1);
        const int buf = kt & 1;
        const u16 (*ml)[32] = (region < 2) ? act_lds[buf] : w_lds[buf];
        const u16 (*nl)[32] = (region < 2) ? w_lds[buf]   : act_lds[buf];
        bf16x8 mf[4], nf[4];
        #pragma unroll
        for (int m = 0; m < 4; ++m) mf[m] = ld8(&ml[wr * 64 + m * 16 + lr][aph]);
        #pragma unroll
        for (int n = 0; n < 4; ++n) nf[n] = ld8(&nl[wc * 64 + n * 16 + lr][aph]);
        #pragma unroll
        for (int m = 0; m < 4; ++m)
            #pragma unroll
            for (int n = 0; n < 4; ++n)
                acc[m][n] = MFMA16(mf[m], nf[n], acc[m][n]);
        VMCNT0;
        __syncthreads();
    }

    const float sc = (region == 0) ? QSCALE : 1.0f;   // fold softmax scale into Q
    if (region < 2) {
        u16* dst = region == 0 ? qo : ko;
        #pragma unroll
        for (int m = 0; m < 4; ++m)
            #pragma unroll
            for (int n = 0; n < 4; ++n)
                #pragma unroll
                for (int rr = 0; rr < 4; ++rr) {
                    int grow = act_r0 + wr * 64 + m * 16 + g0 * 4 + rr;
                    int gcol = w_r0 + wc * 64 + n * 16 + lr;
                    size_t di = (size_t)((grow >> 11) * 16 + (gcol >> 6)) * 131072
                              + (size_t)(grow & 2047) * 64 + (gcol & 63);
                    dst[di] = f2bf(acc[m][n][rr] * sc);
                }
    } else {
        #pragma unroll
        for (int m = 0; m < 4; ++m)
            #pragma unroll
            for (int n = 0; n < 4; ++n)
                #pragma unroll
                for (int rr = 0; rr < 4; ++rr) {
                    int dvi = w_r0 + wr * 64 + m * 16 + g0 * 4 + rr;
                    int li  = act_r0 + wc * 64 + n * 16 + lr;
                    vTo[(size_t)dvi * 4096 + li] = f2bf(acc[m][n][rr]);
                }
    }
}

// ---------------- out projection (R12/R13 proven, XCD-pinned 1D grid) ------
__global__ __launch_bounds__(256)
void k_out(const u16* __restrict__ A, const u16* __restrict__ Bw,
           float* __restrict__ C) {
    constexpr int K = 1024;
    __shared__ u16 a_lds[2][128][32];
    __shared__ u16 b_lds[2][64][32];

    const int tid = threadIdx.x, lane = tid & 63, w = tid >> 6;
    const int wr = w >> 1, wc = w & 1, lr = lane & 15, g0 = lane >> 4;
    const int bid = blockIdx.x;
    const int m0 = (bid & 31) * 128, n0 = (bid >> 5) * 64;

    const int srow = lane >> 2;
    const int scol = ((lane & 3) ^ ((lane >> 3) & 3)) * 8;
    const int aph = (g0 ^ ((lr >> 1) & 3)) * 8;

    auto stage = [&](int kt, int buf) {
        #pragma unroll
        for (int c = 0; c < 2; ++c) {
            int rb = w * 16 + c * 64;
            stage16(A + (size_t)(m0 + rb + srow) * K + kt * 32 + scol,
                    &a_lds[buf][rb][0], lane);
        }
        int rb2 = w * 16;
        stage16(Bw + (size_t)(n0 + rb2 + srow) * K + kt * 32 + scol,
                &b_lds[buf][rb2][0], lane);
    };

    f32x4 acc[4][2] = {};
    stage(0, 0);
    VMCNT0;
    __syncthreads();

    for (int kt = 0; kt < 32; ++kt) {
        if (kt + 1 < 32) stage(kt + 1, (kt + 1) & 1);
        const int buf = kt & 1;
        bf16x8 mf[4], nf[2];
        #pragma unroll
        for (int m = 0; m < 4; ++m) mf[m] = ld8(&a_lds[buf][wr * 64 + m * 16 + lr][aph]);
        #pragma unroll
        for (int n = 0; n < 2; ++n) nf[n] = ld8(&b_lds[buf][wc * 32 + n * 16 + lr][aph]);
        #pragma unroll
        for (int m = 0; m < 4; ++m)
            #pragma unroll
            for (int n = 0; n < 2; ++n)
                acc[m][n] = MFMA16(mf[m], nf[n], acc[m][n]);
        VMCNT0;
        __syncthreads();
    }

    #pragma unroll
    for (int m = 0; m < 4; ++m)
        #pragma unroll
        for (int n = 0; n < 2; ++n)
            #pragma unroll
            for (int rr = 0; rr < 4; ++rr) {
                int grow = m0 + wr * 64 + m * 16 + g0 * 4 + rr;
                int gcol = n0 + wc * 32 + n * 16 + lr;
                C[(size_t)grow * 1024 + gcol] = acc[m][n][rr];
            }
}

// ---------------- fused attention -----------------------------------------
// 1024 blocks XCD-pinned, 4 waves x 16 q-rows, 3 blocks/CU (48 KB LDS).
// Phase 1: KVBLK=128, THREE buffers, 2-deep prefetch: at iter t issue
// stage(t+2), drain only stage(t+1) (vmcnt(4)), raw barrier -- each load
// gets ~2 iterations of cover. Phase 2: R15 single-barrier dbuf loop.
__global__ __launch_bounds__(256, 3)
void attn_kernel(const u16* __restrict__ qw, const u16* __restrict__ kw,
                 const u16* __restrict__ vT, float* __restrict__ attn_o,
                 u16* __restrict__ ctx_o) {
    constexpr int L = 2048;
    // union: phase1 k1 x3 [128][64] (49152B) | phase2 k2 x2 (16K) + vt x2 (16K)
    // + p @32768 (9216B). Scalar LDS pointers only (no pointer arrays).
    __shared__ __attribute__((aligned(16))) char smem[49152];
    typedef u16 KRow[64];
    KRow* k1b0 = (KRow*)smem;                         // phase1 buf0 [128][64]
    KRow* k1b1 = (KRow*)(smem + 16384);               // phase1 buf1 [128][64]
    KRow* k1b2 = (KRow*)(smem + 32768);               // phase1 buf2 [128][64]
    KRow* k2b0 = (KRow*)smem;                         // phase2 K buf0 [64][64]
    KRow* k2b1 = (KRow*)(smem + 8192);                // phase2 K buf1 [64][64]
    KRow* vtb0 = (KRow*)(smem + 16384);               // phase2 V buf0 [64][64]
    KRow* vtb1 = (KRow*)(smem + 24576);               // phase2 V buf1 [64][64]
    typedef u16 PRow[72];
    PRow* pl = (PRow*)(smem + 32768);                 // p[4*16][72]

    const int tid = threadIdx.x, w = tid >> 6, lane = tid & 63;
    const int bid = blockIdx.x;
    const int bh = (bid & 7) + 8 * (bid >> 8);     // XCD-pinned
    const int qb = (bid >> 3) & 31;
    const int b = bh >> 4, h = bh & 15;
    const int qr0 = qb * 64 + w * 16;
    const int lr = lane & 15, g0 = lane >> 4;

    const u16* kbh = kw + (size_t)bh * L * 64;
    const u16* vbh = vT + (size_t)(h * 64) * 4096 + b * 2048;

    const int srow8 = lane >> 3;                   // 0..7
    const int scol8 = ((lane & 7) ^ srow8) * 8;    // pre-swizzled src granule
    const int kph0 = (g0 ^ (lr & 7)) * 8;
    const int kph1 = ((g0 + 4) ^ (lr & 7)) * 8;

    size_t qbase = ((size_t)bh * L + qr0 + lr) * 64 + g0 * 8;
    bf16x8 aq0 = ld8(qw + qbase);
    bf16x8 aq1 = ld8(qw + qbase + 32);

    PRow* plw = pl + w * 16;

    // ------- phase 1: softmax denominator, KVBLK=128, 3-buf 2-deep ---------
    auto stageK1 = [&](int kv, KRow* dst) {
        #pragma unroll
        for (int c = 0; c < 4; ++c) {
            int rb = c * 32 + w * 8;
            stage16(kbh + (size_t)(kv + rb + srow8) * 64 + scol8, &dst[rb][0], lane);
        }
    };
    float ssum = 0.f;
    stageK1(0, k1b0);
    stageK1(128, k1b1);
    VMCNT4;                            // drain tile0, leave tile1 in flight
    SCHED0; RAWBAR; SCHED0;
    for (int t = 0; t < 16; ++t) {
        // issue stage(t+2) into buf[(t+2)%3] (last read at iter t-1, safe)
        if (t + 2 < 16)
            stageK1((t + 2) * 128, ((t + 2) % 3 == 0) ? k1b0
                                  : ((t + 2) % 3 == 1) ? k1b1 : k1b2);
        KRow* kb = (t % 3 == 0) ? k1b0 : (t % 3 == 1) ? k1b1 : k1b2;
        f32x4 sacc[8] = {};
        #pragma unroll
        for (int n = 0; n < 8; ++n) {
            const u16* krow = &kb[n * 16 + lr][0];
            sacc[n] = MFMA16(ld8(krow + kph0), aq0, sacc[n]);   // swapped: S^T
            sacc[n] = MFMA16(ld8(krow + kph1), aq1, sacc[n]);
        }
        #pragma unroll
        for (int n = 0; n < 8; ++n)
            #pragma unroll
            for (int rr = 0; rr < 4; ++rr)
                ssum += EXP2(sacc[n][rr]);
        // drain stage(t+1); keep stage(t+2) in flight across the barrier.
        // tail (no t+2 issued): drain fully so tile t+1 is complete.
        if (t + 2 < 16) { VMCNT4; } else { VMCNT0; }
        SCHED0; RAWBAR; SCHED0;
    }
    ssum += __shfl_xor(ssum, 16);
    ssum += __shfl_xor(ssum, 32);
    const float rinv = 1.f / ssum;

    // ---------------- phase 2: single-barrier dbuf loop (R15) --------------
    auto stageK = [&](int kv, KRow* dst) {
        #pragma unroll
        for (int c = 0; c < 2; ++c) {
            int rb = c * 32 + w * 8;
            stage16(kbh + (size_t)(kv + rb + srow8) * 64 + scol8, &dst[rb][0], lane);
        }
    };
    auto stageV = [&](int kv, KRow* dst) {
        #pragma unroll
        for (int c = 0; c < 2; ++c) {
            int rb = w * 16 + c * 8;
            stage16(vbh + (size_t)(rb + srow8) * 4096 + kv + scol8, &dst[rb][0], lane);
        }
    };

    f32x4 cacc[4] = {};
    float* attn_b = attn_o + (size_t)bh * L * L;
    stageK(0, k2b0);
    stageV(0, vtb0);
    VMCNT0;
    __syncthreads();

    for (int t = 0; t < 32; ++t) {
        const int kv = t * 64, buf = t & 1;
        KRow* kcur = buf ? k2b1 : k2b0;
        KRow* vcur = buf ? vtb1 : vtb0;
        // loads for t+1 FIRST (oldest in vm queue -> drained by vmcnt(4))
        if (t + 1 < 32) {
            stageV(kv + 64, buf ? vtb0 : vtb1);
            stageK(kv + 64, buf ? k2b0 : k2b1);
        }
        SCHED0;                        // keep stores below the gll issues
        // deferred NT writeout of tile t-1 (stores ride past the barrier)
        if (t > 0) {
            const int kvp = kv - 64;
            #pragma unroll
            for (int rep = 0; rep < 4; ++rep) {
                int row = rep * 4 + g0;
                u16x4 pv4 = *(const u16x4*)&plw[row][lr * 4];
                f32x4 f0 = { bf2f(pv4[0]), bf2f(pv4[1]), bf2f(pv4[2]), bf2f(pv4[3]) };
                __builtin_nontemporal_store(
                    f0, (f32x4*)(attn_b + (size_t)(qr0 + row) * L + kvp + lr * 4));
            }
        }
        // QK^T on current tile (kcur guaranteed by previous barrier)
        f32x4 sacc[4] = {};
        #pragma unroll
        for (int n = 0; n < 4; ++n) {
            const u16* krow = &kcur[n * 16 + lr][0];
            sacc[n] = MFMA16(ld8(krow + kph0), aq0, sacc[n]);
            sacc[n] = MFMA16(ld8(krow + kph1), aq1, sacc[n]);
        }
        // normalized P (bf16) -> p_lds[q=lr][kv] (per-wave region)
        #pragma unroll
        for (int n = 0; n < 4; ++n) {
            float p0 = EXP2(sacc[n][0]) * rinv;
            float p1 = EXP2(sacc[n][1]) * rinv;
            float p2 = EXP2(sacc[n][2]) * rinv;
            float p3 = EXP2(sacc[n][3]) * rinv;
            u16x4 pk = { f2bf(p0), f2bf(p1), f2bf(p2), f2bf(p3) };
            *(u16x4*)&plw[lr][n * 16 + g0 * 4] = pk;
        }
        // PV: ctx[q][dv] += P[q][kv] * V^T[dv][kv]  (vcur from prev barrier)
        #pragma unroll
        for (int kk = 0; kk < 2; ++kk) {
            bf16x8 ap = ld8(&plw[lr][kk * 32 + g0 * 8]);
            const int vph = ((kk * 4 + g0) ^ (lr & 7)) * 8;
            #pragma unroll
            for (int n2 = 0; n2 < 4; ++n2) {
                bf16x8 bv = ld8(&vcur[n2 * 16 + lr][vph]);
                cacc[n2] = MFMA16(ap, bv, cacc[n2]);
            }
        }
        // drain this iteration's 4 gll loads; stores(t-1) stay in flight
        if (t == 0) { VMCNT0; } else { VMCNT4; }
        SCHED0; RAWBAR; SCHED0;        // the ONE barrier per tile
    }
    // final NT writeout (tile 31)
    #pragma unroll
    for (int rep = 0; rep < 4; ++rep) {
        int row = rep * 4 + g0;
        u16x4 pv4 = *(const u16x4*)&plw[row][lr * 4];
        f32x4 f0 = { bf2f(pv4[0]), bf2f(pv4[1]), bf2f(pv4[2]), bf2f(pv4[3]) };
        __builtin_nontemporal_store(
            f0, (f32x4*)(attn_b + (size_t)(qr0 + row) * L + (L - 64) + lr * 4));
    }

    // ctx -> ws in [b][l][h*64+dv] layout (normal stores; consumed by k_out)
    #pragma unroll
    for (int n2 = 0; n2 < 4; ++n2)
        #pragma unroll
        for (int rr = 0; rr < 4; ++rr)
            ctx_o[((size_t)b * L + qr0 + g0 * 4 + rr) * 1024 + h * 64 + n2 * 16 + lr]
                = f2bf(cacc[n2][rr]);
}

// ---------------------------------------------------------------------------
extern "C" void kernel_launch(void* const* d_in, const int* in_sizes, int n_in,
                              void* d_out, int out_size, void* d_ws, size_t ws_size,
                              hipStream_t stream) {
    const float* key   = (const float*)d_in[0];
    const float* value = (const float*)d_in[1];
    const float* query = (const float*)d_in[2];
    const float* wq    = (const float*)d_in[3];
    const float* wk    = (const float*)d_in[4];
    const float* wv    = (const float*)d_in[5];
    const float* wo    = (const float*)d_in[6];

    char* ws = (char*)d_ws;
    const size_t MB = 1024 * 1024;
    u16* wq_b = (u16*)(ws + 0 * MB);
    u16* wk_b = (u16*)(ws + 2 * MB);
    u16* wv_b = (u16*)(ws + 4 * MB);
    u16* wo_b = (u16*)(ws + 6 * MB);
    u16* q_b  = (u16*)(ws + 8 * MB);
    u16* k_b  = (u16*)(ws + 16 * MB);
    u16* vT_b = (u16*)(ws + 24 * MB);
    u16* ctx_b= (u16*)(ws + 32 * MB);

    cvt_w<<<4096, 256, 0, stream>>>(wq, wk, wv, wo, wq_b, wk_b, wv_b, wo_b);

    k_qkv<<<768, 256, 0, stream>>>(query, key, value, wq_b, wk_b, wv_b,
                                   q_b, k_b, vT_b);

    float* attn_out = (float*)d_out + 4194304;
    attn_kernel<<<dim3(1024), 256, 0, stream>>>(q_b, k_b, vT_b, attn_out, ctx_b);

    k_out<<<dim3(512), 256, 0, stream>>>(ctx_b, wo_b, (float*)d_out);
}

// Round 17
// 195.862 us; speedup vs baseline: 1.0099x; 1.0099x over previous
//
#include <hip/hip_runtime.h>

// ---------------------------------------------------------------------------
// MHA forward. B=2 L=2048 D=1024 H=16 dk=dv=64.
// d_out = [out: 4194304 f32][attn: 134217728 f32]
// ws (40MB): wq|wk|wv|wo bf16 @0,2,4,6MB; q_b@8; k_b@16; vT@24; ctx@32
// Order: cvt_w -> fused QKV (Q prescaled by 0.125/ln2) -> attn (exp2) -> out
// attn = R15 (phase1 KVBLK=128 dbuf; phase2 single-barrier dbuf, NT stores).
// k_qkv: T14 async-STAGE split -- act f32 loads issued BEFORE the MFMA block,
// cvt+ds_write after (load latency hides under MFMAs).
// ---------------------------------------------------------------------------

typedef unsigned short u16;
typedef unsigned int   u32;
typedef __attribute__((ext_vector_type(4))) float f32x4;
typedef __attribute__((ext_vector_type(8))) u16   u16x8;
typedef __attribute__((ext_vector_type(4))) u16   u16x4;
typedef __attribute__((ext_vector_type(8))) __bf16 bf16x8;

#define MFMA16(a, b, c) __builtin_amdgcn_mfma_f32_16x16x32_bf16((a), (b), (c), 0, 0, 0)
#define VMCNT0 asm volatile("s_waitcnt vmcnt(0)" ::: "memory")
#define VMCNT4 asm volatile("s_waitcnt vmcnt(4)" ::: "memory")
#define SCHED0 __builtin_amdgcn_sched_barrier(0)
#define RAWBAR __builtin_amdgcn_s_barrier()

#if defined(__has_builtin)
#if __has_builtin(__builtin_amdgcn_global_load_lds)
#define HAS_GLL 1
#endif
#if __has_builtin(__builtin_amdgcn_exp2f)
#define EXP2(x) __builtin_amdgcn_exp2f(x)
#endif
#endif
#ifndef HAS_GLL
#define HAS_GLL 0
#endif
#ifndef EXP2
#define EXP2(x) __expf((x) * 0.69314718056f)
#endif

#define QSCALE 0.18033688011116f   // 0.125 / ln(2)

__device__ __forceinline__ u16 f2bf(float x) {
    u32 u = __builtin_bit_cast(u32, x);
    u += 0x7fffu + ((u >> 16) & 1u);   // RNE
    return (u16)(u >> 16);
}
__device__ __forceinline__ float bf2f(u16 x) {
    u32 u = ((u32)x) << 16;
    return __builtin_bit_cast(float, u);
}
__device__ __forceinline__ bf16x8 ld8(const u16* p) {
    return __builtin_bit_cast(bf16x8, *(const u16x8*)p);
}

// async global->LDS, 16B per lane; lds_base wave-uniform, HW adds lane*16.
__device__ __forceinline__ void stage16(const u16* g, u16* lds_base, int lane) {
#if HAS_GLL
    (void)lane;
    __builtin_amdgcn_global_load_lds(
        (const __attribute__((address_space(1))) u32*)g,
        (__attribute__((address_space(3))) u32*)lds_base, 16, 0, 0);
#else
    *(u16x8*)((char*)lds_base + lane * 16) = *(const u16x8*)g;
#endif
}

// ---------------- fp32 -> bf16 conversion (weights only) -------------------
__global__ __launch_bounds__(256) void cvt_w(
    const float* __restrict__ wq, const float* __restrict__ wk,
    const float* __restrict__ wv, const float* __restrict__ wo,
    u16* __restrict__ wqb, u16* __restrict__ wkb,
    u16* __restrict__ wvb, u16* __restrict__ wob) {
    int bid = blockIdx.x;
    const float* src; u16* dst; int base;
    if      (bid < 1024) { src = wq; dst = wqb; base = bid; }
    else if (bid < 2048) { src = wk; dst = wkb; base = bid - 1024; }
    else if (bid < 3072) { src = wv; dst = wvb; base = bid - 2048; }
    else                 { src = wo; dst = wob; base = bid - 3072; }
    int i = (base * 256 + threadIdx.x) * 4;
    float4 v = *(const float4*)(src + i);
    u16x4 h = { f2bf(v.x), f2bf(v.y), f2bf(v.z), f2bf(v.w) };
    *(u16x4*)(dst + i) = h;
}

// ---------------- fused QKV projection (XCD-pinned, T14 act staging) -------
__global__ __launch_bounds__(256)
void k_qkv(const float* __restrict__ qa, const float* __restrict__ ka,
           const float* __restrict__ va,
           const u16* __restrict__ wqp, const u16* __restrict__ wkp,
           const u16* __restrict__ wvp,
           u16* __restrict__ qo, u16* __restrict__ ko, u16* __restrict__ vTo) {
    constexpr int K = 1024;
    __shared__ u16 act_lds[2][128][32];
    __shared__ u16 w_lds[2][128][32];

    const int tid = threadIdx.x, lane = tid & 63, w = tid >> 6;
    const int wr = w >> 1, wc = w & 1, lr = lane & 15, g0 = lane >> 4;
    const int bid0 = blockIdx.x;
    const int kk = bid0 / 96, gg = bid0 % 96;      // XCD-pinned remap
    const int wgid = gg * 8 + kk;
    const int region = wgid >> 8, r = wgid & 255;
    const int act_r0 = (r >> 3) * 128, w_r0 = (r & 7) * 128;

    const float* actp = region == 0 ? qa : region == 1 ? ka : va;
    const u16*   wp   = region == 0 ? wqp : region == 1 ? wkp : wvp;

    const int srow = lane >> 2;
    const int scol = ((lane & 3) ^ ((lane >> 3) & 3)) * 8;
    const int arow = tid >> 1, ac0 = (tid & 1) * 16, lg0 = (tid & 1) * 2;
    const int apg0 = ((lg0)     ^ ((arow >> 1) & 3)) * 8;
    const int apg1 = ((lg0 + 1) ^ ((arow >> 1) & 3)) * 8;
    const int aph = (g0 ^ ((lr >> 1) & 3)) * 8;

    // T14 split: (a) issue weight glls + act f32 loads into regs;
    auto stage_w = [&](int kt, int buf) {
        #pragma unroll
        for (int c = 0; c < 2; ++c) {
            int rb = w * 16 + c * 64;
            stage16(wp + (size_t)(w_r0 + rb + srow) * K + kt * 32 + scol,
                    &w_lds[buf][rb][0], lane);
        }
    };
    f32x4 r0, r1, r2, r3;
    auto act_load = [&](int kt) {
        const float* as = actp + (size_t)(act_r0 + arow) * K + kt * 32 + ac0;
        r0 = *(const f32x4*)as;
        r1 = *(const f32x4*)(as + 4);
        r2 = *(const f32x4*)(as + 8);
        r3 = *(const f32x4*)(as + 12);
    };
    // (b) cvt + ds_write (first USE of the loads -> waitcnt lands here)
    auto act_write = [&](int buf) {
        u16x8 h0 = { f2bf(r0[0]), f2bf(r0[1]), f2bf(r0[2]), f2bf(r0[3]),
                     f2bf(r1[0]), f2bf(r1[1]), f2bf(r1[2]), f2bf(r1[3]) };
        u16x8 h1 = { f2bf(r2[0]), f2bf(r2[1]), f2bf(r2[2]), f2bf(r2[3]),
                     f2bf(r3[0]), f2bf(r3[1]), f2bf(r3[2]), f2bf(r3[3]) };
        *(u16x8*)&act_lds[buf][arow][apg0] = h0;
        *(u16x8*)&act_lds[buf][arow][apg1] = h1;
    };

    f32x4 acc[4][4] = {};
    stage_w(0, 0);
    act_load(0);
    act_write(0);
    VMCNT0;
    __syncthreads();

    for (int kt = 0; kt < 32; ++kt) {
        const int buf = kt & 1;
        // issue next-tile loads FIRST (latency hides under this tile's MFMAs)
        if (kt + 1 < 32) {
            stage_w(kt + 1, buf ^ 1);
            act_load(kt + 1);
        }
        const u16 (*ml)[32] = (region < 2) ? act_lds[buf] : w_lds[buf];
        const u16 (*nl)[32] = (region < 2) ? w_lds[buf]   : act_lds[buf];
        bf16x8 mf[4], nf[4];
        #pragma unroll
        for (int m = 0; m < 4; ++m) mf[m] = ld8(&ml[wr * 64 + m * 16 + lr][aph]);
        #pragma unroll
        for (int n = 0; n < 4; ++n) nf[n] = ld8(&nl[wc * 64 + n * 16 + lr][aph]);
        #pragma unroll
        for (int m = 0; m < 4; ++m)
            #pragma unroll
            for (int n = 0; n < 4; ++n)
                acc[m][n] = MFMA16(mf[m], nf[n], acc[m][n]);
        // now consume the act loads (waitcnt here, after MFMA cover)
        if (kt + 1 < 32) act_write(buf ^ 1);
        VMCNT0;            // drain the 2 weight glls of kt+1
        __syncthreads();
    }

    const float sc = (region == 0) ? QSCALE : 1.0f;   // fold softmax scale into Q
    if (region < 2) {
        u16* dst = region == 0 ? qo : ko;
        #pragma unroll
        for (int m = 0; m < 4; ++m)
            #pragma unroll
            for (int n = 0; n < 4; ++n)
                #pragma unroll
                for (int rr = 0; rr < 4; ++rr) {
                    int grow = act_r0 + wr * 64 + m * 16 + g0 * 4 + rr;
                    int gcol = w_r0 + wc * 64 + n * 16 + lr;
                    size_t di = (size_t)((grow >> 11) * 16 + (gcol >> 6)) * 131072
                              + (size_t)(grow & 2047) * 64 + (gcol & 63);
                    dst[di] = f2bf(acc[m][n][rr] * sc);
                }
    } else {
        #pragma unroll
        for (int m = 0; m < 4; ++m)
            #pragma unroll
            for (int n = 0; n < 4; ++n)
                #pragma unroll
                for (int rr = 0; rr < 4; ++rr) {
                    int dvi = w_r0 + wr * 64 + m * 16 + g0 * 4 + rr;
                    int li  = act_r0 + wc * 64 + n * 16 + lr;
                    vTo[(size_t)dvi * 4096 + li] = f2bf(acc[m][n][rr]);
                }
    }
}

// ---------------- out projection (R12/R13 proven, XCD-pinned 1D grid) ------
__global__ __launch_bounds__(256)
void k_out(const u16* __restrict__ A, const u16* __restrict__ Bw,
           float* __restrict__ C) {
    constexpr int K = 1024;
    __shared__ u16 a_lds[2][128][32];
    __shared__ u16 b_lds[2][64][32];

    const int tid = threadIdx.x, lane = tid & 63, w = tid >> 6;
    const int wr = w >> 1, wc = w & 1, lr = lane & 15, g0 = lane >> 4;
    const int bid = blockIdx.x;
    const int m0 = (bid & 31) * 128, n0 = (bid >> 5) * 64;

    const int srow = lane >> 2;
    const int scol = ((lane & 3) ^ ((lane >> 3) & 3)) * 8;
    const int aph = (g0 ^ ((lr >> 1) & 3)) * 8;

    auto stage = [&](int kt, int buf) {
        #pragma unroll
        for (int c = 0; c < 2; ++c) {
            int rb = w * 16 + c * 64;
            stage16(A + (size_t)(m0 + rb + srow) * K + kt * 32 + scol,
                    &a_lds[buf][rb][0], lane);
        }
        int rb2 = w * 16;
        stage16(Bw + (size_t)(n0 + rb2 + srow) * K + kt * 32 + scol,
                &b_lds[buf][rb2][0], lane);
    };

    f32x4 acc[4][2] = {};
    stage(0, 0);
    VMCNT0;
    __syncthreads();

    for (int kt = 0; kt < 32; ++kt) {
        if (kt + 1 < 32) stage(kt + 1, (kt + 1) & 1);
        const int buf = kt & 1;
        bf16x8 mf[4], nf[2];
        #pragma unroll
        for (int m = 0; m < 4; ++m) mf[m] = ld8(&a_lds[buf][wr * 64 + m * 16 + lr][aph]);
        #pragma unroll
        for (int n = 0; n < 2; ++n) nf[n] = ld8(&b_lds[buf][wc * 32 + n * 16 + lr][aph]);
        #pragma unroll
        for (int m = 0; m < 4; ++m)
            #pragma unroll
            for (int n = 0; n < 2; ++n)
                acc[m][n] = MFMA16(mf[m], nf[n], acc[m][n]);
        VMCNT0;
        __syncthreads();
    }

    #pragma unroll
    for (int m = 0; m < 4; ++m)
        #pragma unroll
        for (int n = 0; n < 2; ++n)
            #pragma unroll
            for (int rr = 0; rr < 4; ++rr) {
                int grow = m0 + wr * 64 + m * 16 + g0 * 4 + rr;
                int gcol = n0 + wc * 32 + n * 16 + lr;
                C[(size_t)grow * 1024 + gcol] = acc[m][n][rr];
            }
}

// ---------------- fused attention (R15 verbatim) ---------------------------
// 1024 blocks XCD-pinned, 4 waves x 16 q-rows, 3 blocks/CU (41.9 KB LDS).
// Phase 1: KVBLK=128 dbuf denominator pass. Phase 2: SINGLE barrier per
// tile; K and V both double-buffered; NT stores(t-1) ride past the barrier
// via vmcnt(4) (loads issued first = oldest = drained).
__global__ __launch_bounds__(256, 3)
void attn_kernel(const u16* __restrict__ qw, const u16* __restrict__ kw,
                 const u16* __restrict__ vT, float* __restrict__ attn_o,
                 u16* __restrict__ ctx_o) {
    constexpr int L = 2048;
    __shared__ __attribute__((aligned(16))) char smem[41984];
    typedef u16 KRow[64];
    KRow* k1b0 = (KRow*)smem;                         // phase1 buf0 [128][64]
    KRow* k1b1 = (KRow*)(smem + 16384);               // phase1 buf1 [128][64]
    KRow* k2b0 = (KRow*)smem;                         // phase2 K buf0 [64][64]
    KRow* k2b1 = (KRow*)(smem + 8192);                // phase2 K buf1 [64][64]
    KRow* vtb0 = (KRow*)(smem + 16384);               // phase2 V buf0 [64][64]
    KRow* vtb1 = (KRow*)(smem + 24576);               // phase2 V buf1 [64][64]
    typedef u16 PRow[72];
    PRow* pl = (PRow*)(smem + 32768);                 // p[4*16][72]

    const int tid = threadIdx.x, w = tid >> 6, lane = tid & 63;
    const int bid = blockIdx.x;
    const int bh = (bid & 7) + 8 * (bid >> 8);     // XCD-pinned
    const int qb = (bid >> 3) & 31;
    const int b = bh >> 4, h = bh & 15;
    const int qr0 = qb * 64 + w * 16;
    const int lr = lane & 15, g0 = lane >> 4;

    const u16* kbh = kw + (size_t)bh * L * 64;
    const u16* vbh = vT + (size_t)(h * 64) * 4096 + b * 2048;

    const int srow8 = lane >> 3;                   // 0..7
    const int scol8 = ((lane & 7) ^ srow8) * 8;    // pre-swizzled src granule
    const int kph0 = (g0 ^ (lr & 7)) * 8;
    const int kph1 = ((g0 + 4) ^ (lr & 7)) * 8;

    size_t qbase = ((size_t)bh * L + qr0 + lr) * 64 + g0 * 8;
    bf16x8 aq0 = ld8(qw + qbase);
    bf16x8 aq1 = ld8(qw + qbase + 32);

    PRow* plw = pl + w * 16;

    // ---------------- phase 1: softmax denominator, KVBLK=128 --------------
    auto stageK1 = [&](int kv, KRow* dst) {
        #pragma unroll
        for (int c = 0; c < 4; ++c) {
            int rb = c * 32 + w * 8;
            stage16(kbh + (size_t)(kv + rb + srow8) * 64 + scol8, &dst[rb][0], lane);
        }
    };
    float ssum = 0.f;
    stageK1(0, k1b0);
    VMCNT0;
    __syncthreads();
    for (int t = 0; t < 16; ++t) {
        if (t + 1 < 16) stageK1((t + 1) * 128, (t & 1) ? k1b0 : k1b1);
        KRow* kb = (t & 1) ? k1b1 : k1b0;
        f32x4 sacc[8] = {};
        #pragma unroll
        for (int n = 0; n < 8; ++n) {
            const u16* krow = &kb[n * 16 + lr][0];
            sacc[n] = MFMA16(ld8(krow + kph0), aq0, sacc[n]);   // swapped: S^T
            sacc[n] = MFMA16(ld8(krow + kph1), aq1, sacc[n]);
        }
        #pragma unroll
        for (int n = 0; n < 8; ++n)
            #pragma unroll
            for (int rr = 0; rr < 4; ++rr)
                ssum += EXP2(sacc[n][rr]);
        VMCNT0;            // prefetch had 16 MFMA + 32 exp of cover
        __syncthreads();
    }
    ssum += __shfl_xor(ssum, 16);
    ssum += __shfl_xor(ssum, 32);
    const float rinv = 1.f / ssum;

    // ---------------- phase 2: single-barrier dbuf loop ---------------------
    auto stageK = [&](int kv, KRow* dst) {
        #pragma unroll
        for (int c = 0; c < 2; ++c) {
            int rb = c * 32 + w * 8;
            stage16(kbh + (size_t)(kv + rb + srow8) * 64 + scol8, &dst[rb][0], lane);
        }
    };
    auto stageV = [&](int kv, KRow* dst) {
        #pragma unroll
        for (int c = 0; c < 2; ++c) {
            int rb = w * 16 + c * 8;
            stage16(vbh + (size_t)(rb + srow8) * 4096 + kv + scol8, &dst[rb][0], lane);
        }
    };

    f32x4 cacc[4] = {};
    float* attn_b = attn_o + (size_t)bh * L * L;
    stageK(0, k2b0);
    stageV(0, vtb0);
    VMCNT0;
    __syncthreads();

    for (int t = 0; t < 32; ++t) {
        const int kv = t * 64, buf = t & 1;
        KRow* kcur = buf ? k2b1 : k2b0;
        KRow* vcur = buf ? vtb1 : vtb0;
        // loads for t+1 FIRST (oldest in vm queue -> drained by vmcnt(4))
        if (t + 1 < 32) {
            stageV(kv + 64, buf ? vtb0 : vtb1);
            stageK(kv + 64, buf ? k2b0 : k2b1);
        }
        SCHED0;                        // keep stores below the gll issues
        // deferred NT writeout of tile t-1 (stores ride past the barrier)
        if (t > 0) {
            const int kvp = kv - 64;
            #pragma unroll
            for (int rep = 0; rep < 4; ++rep) {
                int row = rep * 4 + g0;
                u16x4 pv4 = *(const u16x4*)&plw[row][lr * 4];
                f32x4 f0 = { bf2f(pv4[0]), bf2f(pv4[1]), bf2f(pv4[2]), bf2f(pv4[3]) };
                __builtin_nontemporal_store(
                    f0, (f32x4*)(attn_b + (size_t)(qr0 + row) * L + kvp + lr * 4));
            }
        }
        // QK^T on current tile (kcur guaranteed by previous barrier)
        f32x4 sacc[4] = {};
        #pragma unroll
        for (int n = 0; n < 4; ++n) {
            const u16* krow = &kcur[n * 16 + lr][0];
            sacc[n] = MFMA16(ld8(krow + kph0), aq0, sacc[n]);
            sacc[n] = MFMA16(ld8(krow + kph1), aq1, sacc[n]);
        }
        // normalized P (bf16) -> p_lds[q=lr][kv] (per-wave region)
        #pragma unroll
        for (int n = 0; n < 4; ++n) {
            float p0 = EXP2(sacc[n][0]) * rinv;
            float p1 = EXP2(sacc[n][1]) * rinv;
            float p2 = EXP2(sacc[n][2]) * rinv;
            float p3 = EXP2(sacc[n][3]) * rinv;
            u16x4 pk = { f2bf(p0), f2bf(p1), f2bf(p2), f2bf(p3) };
            *(u16x4*)&plw[lr][n * 16 + g0 * 4] = pk;
        }
        // PV: ctx[q][dv] += P[q][kv] * V^T[dv][kv]  (vcur from prev barrier)
        #pragma unroll
        for (int kk = 0; kk < 2; ++kk) {
            bf16x8 ap = ld8(&plw[lr][kk * 32 + g0 * 8]);
            const int vph = ((kk * 4 + g0) ^ (lr & 7)) * 8;
            #pragma unroll
            for (int n2 = 0; n2 < 4; ++n2) {
                bf16x8 bv = ld8(&vcur[n2 * 16 + lr][vph]);
                cacc[n2] = MFMA16(ap, bv, cacc[n2]);
            }
        }
        // drain this iteration's 4 gll loads; stores(t-1) stay in flight
        if (t == 0) { VMCNT0; } else { VMCNT4; }
        SCHED0; RAWBAR; SCHED0;        // the ONE barrier per tile
    }
    // final NT writeout (tile 31)
    #pragma unroll
    for (int rep = 0; rep < 4; ++rep) {
        int row = rep * 4 + g0;
        u16x4 pv4 = *(const u16x4*)&plw[row][lr * 4];
        f32x4 f0 = { bf2f(pv4[0]), bf2f(pv4[1]), bf2f(pv4[2]), bf2f(pv4[3]) };
        __builtin_nontemporal_store(
            f0, (f32x4*)(attn_b + (size_t)(qr0 + row) * L + (L - 64) + lr * 4));
    }

    // ctx -> ws in [b][l][h*64+dv] layout (normal stores; consumed by k_out)
    #pragma unroll
    for (int n2 = 0; n2 < 4; ++n2)
        #pragma unroll
        for (int rr = 0; rr < 4; ++rr)
            ctx_o[((size_t)b * L + qr0 + g0 * 4 + rr) * 1024 + h * 64 + n2 * 16 + lr]
                = f2bf(cacc[n2][rr]);
}

// ---------------------------------------------------------------------------
extern "C" void kernel_launch(void* const* d_in, const int* in_sizes, int n_in,
                              void* d_out, int out_size, void* d_ws, size_t ws_size,
                              hipStream_t stream) {
    const float* key   = (const float*)d_in[0];
    const float* value = (const float*)d_in[1];
    const float* query = (const float*)d_in[2];
    const float* wq    = (const float*)d_in[3];
    const float* wk    = (const float*)d_in[4];
    const float* wv    = (const float*)d_in[5];
    const float* wo    = (const float*)d_in[6];

    char* ws = (char*)d_ws;
    const size_t MB = 1024 * 1024;
    u16* wq_b = (u16*)(ws + 0 * MB);
    u16* wk_b = (u16*)(ws + 2 * MB);
    u16* wv_b = (u16*)(ws + 4 * MB);
    u16* wo_b = (u16*)(ws + 6 * MB);
    u16* q_b  = (u16*)(ws + 8 * MB);
    u16* k_b  = (u16*)(ws + 16 * MB);
    u16* vT_b = (u16*)(ws + 24 * MB);
    u16* ctx_b= (u16*)(ws + 32 * MB);

    cvt_w<<<4096, 256, 0, stream>>>(wq, wk, wv, wo, wq_b, wk_b, wv_b, wo_b);

    k_qkv<<<768, 256, 0, stream>>>(query, key, value, wq_b, wk_b, wv_b,
                                   q_b, k_b, vT_b);

    float* attn_out = (float*)d_out + 4194304;
    attn_kernel<<<dim3(1024), 256, 0, stream>>>(q_b, k_b, vT_b, attn_out, ctx_b);

    k_out<<<dim3(512), 256, 0, stream>>>(ctx_b, wo_b, (float*)d_out);
}